// Round 10
// baseline (226.617 us; speedup 1.0000x reference)
//
#include <hip/hip_runtime.h>
#include <hip/hip_bf16.h>

// Problem constants: B,L,M,D,K,STRIDE = 32,32768,32,128,16,8
#define Bn 32
#define Ln 32768
#define Mn 32
#define Dn 128
#define Pn 4095            // (L - K)/STRIDE + 1

typedef short  bf16x8 __attribute__((ext_vector_type(8)));  // 8 bf16 = 4 VGPRs
typedef float  f32x4  __attribute__((ext_vector_type(4)));

union BU { bf16x8 v; unsigned short u[8]; };

static __device__ __forceinline__ unsigned short f2bf(float f) {
  __hip_bfloat16 h = __float2bfloat16(f);
  return *reinterpret_cast<unsigned short*>(&h);
}

// async 16-B/lane global->LDS DMA. Source must be LINEAR per lane (lane*16)
// or the DMA coalescer fragments into per-sector fetches (R3: 4x FETCH).
static __device__ __forceinline__ void gload_lds16(const float* g, float* l) {
  __builtin_amdgcn_global_load_lds(
      (const __attribute__((address_space(1))) unsigned int*)g,
      (__attribute__((address_space(3))) unsigned int*)l, 16, 0, 0);
}

// ---------------------------------------------------------------------------
// Prep: conv_w (D,M,K) fp32 -> fragment-ready swizzled bf16 in d_ws.
// kk = k*32 + m; B-frag lane d=lane&15, kk=t*32+quad*8+j
//   -> wswz[((kk>>3)*128 + d)*8 + (kk&7)]  (one 16-B load per fragment)
// ---------------------------------------------------------------------------
__global__ __launch_bounds__(256) void prep_w_kernel(const float* __restrict__ w,
                                                     unsigned short* __restrict__ wswz) {
  int idx = blockIdx.x * 256 + threadIdx.x;   // 0..65535
  int j = idx & 7;
  int d = (idx >> 3) & 127;
  int g = idx >> 10;
  int kk = g * 8 + j;
  int k = kk >> 5;
  int m = kk & 31;
  wswz[idx] = f2bf(w[(d << 9) + (m << 4) + k]);   // w[d][m][k]
}

// ---------------------------------------------------------------------------
// Main: 512 threads = 8 waves; wave wv owns d-cols [wv*16, wv*16+16) with the
// FULL-K B operand resident in 64 VGPRs (loaded once). Block owns 128
// patches = 8 quarters of 16 patches (136 rows), x staged fp32 via
// global_load_lds, double-buffered: issue stage Q(q+1) -> K-loop(buf q&1)
// -> epilogue -> barrier. Grid = 32 x 32 = 1024 blocks -> 4 blocks/CU
// (VGPR=64, LDS=39,424 B both fit) = 32 waves/CU for barrier/phase hiding.
//
// LDS layout: quarter = 17 batches of 8 rows (1024 B). Batch bb at float
// offset bb*288 + (bb&7)*4 (128-B pad + 16-B shift per batch); DMA source
// and dest both linear per instruction; the shift spreads the K-loop's
// column-slice ds_read_b128 across all granule columns.
// ---------------------------------------------------------------------------
#define QROWS 136
#define BATCHF 288               // floats per batch slot (1024 B data + 128 B pad)
#define BUFF (16 * BATCHF + 256) // 4864 floats = 19,456 B (batch 16 unpadded)

__global__ __launch_bounds__(512, 4) void gemm_pe_kernel(
    const float* __restrict__ x,          // (B, L, M) fp32
    const float* __restrict__ ts,         // (B, L)    fp32, sorted along L
    const unsigned short* __restrict__ wswz,
    const float* __restrict__ bias,       // (D,)
    float* __restrict__ out) {            // (B, P, D) fp32

  __shared__ float xsf[2][BUFF];          // 2 x 19,456 B
  __shared__ float tsl[128];              // medians for this block's 128 patches

  const int b    = blockIdx.y;
  const int pt   = blockIdx.x;            // 0..31, patches pt*128 .. +127
  const int tid  = threadIdx.x;
  const int lane = tid & 63;
  const int wv   = tid >> 6;              // 0..7
  const int mrow = lane & 15;
  const int quad = lane >> 4;

  const float* xb0 = x + (size_t)b * Ln * Mn;   // row r -> xb0 + r*32 floats

  // ---- resident B operand: 16 fragments = 64 VGPR, loaded ONCE ------------
  // frag t: B[kk = t*32 + quad*8 + j][d0], addr = ((t*4+quad)*128 + d0)*8 + j
  const int d0 = wv * 16 + mrow;
  const unsigned short* bbase = wswz + (((quad << 7) + d0) << 3);
  bf16x8 bw[16];
  #pragma unroll
  for (int t = 0; t < 16; ++t)
    bw[t] = *reinterpret_cast<const bf16x8*>(bbase + t * 4096);

  // ---- ts medians (sorted ts -> median of 16-window = element 7) ----------
  if (tid < 128) tsl[tid] = ts[(size_t)b * Ln + (size_t)(pt * 128 + tid) * 8 + 7];

  // ---- epilogue scalars ---------------------------------------------------
  const float NEG_C = -0.14391156831212810f;            // -ln(10000)/64
  const float div0  = __expf(NEG_C * (float)(d0 >> 1));
  const float phs   = (d0 & 1) ? 1.5707963267948966f : 0.0f;
  const float bias0 = bias[d0];

  // ---- stage macro: LINEAR 1024-B/wave DMA, shifted batch bases -----------
#define STAGE(qq, bf)                                                          \
  do {                                                                         \
    const float* gq = xb0 + (size_t)(pt * 1024 + (qq) * 128) * 32;             \
    _Pragma("unroll")                                                          \
    for (int i = 0; i < 2; ++i) {                                              \
      const int bb = wv * 2 + i;                                               \
      gload_lds16(gq + (size_t)bb * 256 + lane * 4,                            \
                  &xsf[bf][bb * BATCHF + (bb & 7) * 4]);                       \
    }                                                                          \
    if (wv == 0 && pt * 1024 + (qq) * 128 + QROWS <= Ln)                       \
      gload_lds16(gq + 4096 + lane * 4, &xsf[bf][16 * BATCHF]);                \
  } while (0)

  STAGE(0, 0);
  __syncthreads();   // drains vmcnt: Q0 + bw preloads landed

  #pragma unroll 1
  for (int q = 0; q < 8; ++q) {
    if (q < 7) STAGE(q + 1, (q + 1) & 1);
    __builtin_amdgcn_sched_barrier(0);   // pin stage-issue above the K-loop

    // ---- K-loop: 16 steps of K=32 over buf q&1; zero global loads ---------
    const float* xbuf = xsf[q & 1];
    f32x4 acc = {0.f, 0.f, 0.f, 0.f};
    #pragma unroll
    for (int t = 0; t < 16; ++t) {
      // A-frag row r = mrow*8 + t -> batch b0 = mrow + (t>>3), row-in-batch t&7
      const int b0 = mrow + (t >> 3);
      const int fo = b0 * BATCHF + ((b0 & 7) + (t & 7) * 8 + quad * 2) * 4;
      f32x4 af0 = *reinterpret_cast<const f32x4*>(&xbuf[fo]);
      f32x4 af1 = *reinterpret_cast<const f32x4*>(&xbuf[fo + 4]);
      BU bu;
      bu.u[0] = f2bf(af0[0]); bu.u[1] = f2bf(af0[1]);
      bu.u[2] = f2bf(af0[2]); bu.u[3] = f2bf(af0[3]);
      bu.u[4] = f2bf(af1[0]); bu.u[5] = f2bf(af1[1]);
      bu.u[6] = f2bf(af1[2]); bu.u[7] = f2bf(af1[3]);
      acc = __builtin_amdgcn_mfma_f32_16x16x32_bf16(bu.v, bw[t], acc, 0, 0, 0);
    }

    // ---- epilogue: + bias + PE.  C/D: col=lane&15 (=d), row=quad*4+reg ----
    {
      const int plb = quad * 4;
      f32x4 med4 = *reinterpret_cast<const f32x4*>(&tsl[q * 16 + plb]);
      const int pg = pt * 128 + q * 16 + plb;
      float* obase = out + ((size_t)b * Pn + pg) * Dn + d0;
      #pragma unroll
      for (int reg = 0; reg < 4; ++reg) {
        if (pg + reg < Pn) {
          float m = med4[reg];
          obase[reg * Dn] = acc[reg] + bias0 + __sinf(m * div0 + phs);
        }
      }
    }

    __syncthreads();   // drains vmcnt (stage landed under K-loop) + LDS order
  }
#undef STAGE
}

extern "C" void kernel_launch(void* const* d_in, const int* in_sizes, int n_in,
                              void* d_out, int out_size, void* d_ws, size_t ws_size,
                              hipStream_t stream) {
  const float* x      = (const float*)d_in[0];   // (32, 32768, 32)
  const float* ts     = (const float*)d_in[1];   // (32, 32768)
  const float* conv_w = (const float*)d_in[2];   // (128, 32, 16)
  const float* conv_b = (const float*)d_in[3];   // (128,)
  float* out = (float*)d_out;
  unsigned short* wswz = (unsigned short*)d_ws;  // 512*128 bf16 = 128 KiB

  prep_w_kernel<<<256, 256, 0, stream>>>(conv_w, wswz);
  gemm_pe_kernel<<<dim3(32, Bn), 512, 0, stream>>>(x, ts, wswz, conv_b, out);
}

// Round 11
// 226.355 us; speedup vs baseline: 1.0012x; 1.0012x over previous
//
#include <hip/hip_runtime.h>
#include <hip/hip_bf16.h>

// Problem constants: B,L,M,D,K,STRIDE = 32,32768,32,128,16,8
#define Bn 32
#define Ln 32768
#define Mn 32
#define Dn 128
#define Pn 4095            // (L - K)/STRIDE + 1

typedef short  bf16x8 __attribute__((ext_vector_type(8)));  // 8 bf16 = 4 VGPRs
typedef float  f32x4  __attribute__((ext_vector_type(4)));

union BU { bf16x8 v; unsigned short u[8]; };

static __device__ __forceinline__ unsigned short f2bf(float f) {
  __hip_bfloat16 h = __float2bfloat16(f);
  return *reinterpret_cast<unsigned short*>(&h);
}

// async 16-B/lane global->LDS DMA. Source must be LINEAR per lane (lane*16)
// or the DMA coalescer fragments into per-sector fetches (R3: 4x FETCH).
static __device__ __forceinline__ void gload_lds16(const float* g, float* l) {
  __builtin_amdgcn_global_load_lds(
      (const __attribute__((address_space(1))) unsigned int*)g,
      (__attribute__((address_space(3))) unsigned int*)l, 16, 0, 0);
}

// ---------------------------------------------------------------------------
// Prep: conv_w (D,M,K) fp32 -> fragment-ready swizzled bf16 in d_ws.
// kk = k*32 + m; B-frag lane d=lane&15, kk=t*32+quad*8+j
//   -> wswz[((kk>>3)*128 + d)*8 + (kk&7)]  (one 16-B load per fragment)
// ---------------------------------------------------------------------------
__global__ __launch_bounds__(256) void prep_w_kernel(const float* __restrict__ w,
                                                     unsigned short* __restrict__ wswz) {
  int idx = blockIdx.x * 256 + threadIdx.x;   // 0..65535
  int j = idx & 7;
  int d = (idx >> 3) & 127;
  int g = idx >> 10;
  int kk = g * 8 + j;
  int k = kk >> 5;
  int m = kk & 31;
  wswz[idx] = f2bf(w[(d << 9) + (m << 4) + k]);   // w[d][m][k]
}

// ---------------------------------------------------------------------------
// Main: 512 threads = 8 waves; wave wv owns d-cols [wv*16,+16) with the full-K
// B operand resident in 64 VGPRs (loaded once). Block owns 256 patches = 16
// quarters of 16 patches (136 rows), staged via global_load_lds into a
// TRIPLE-buffered LDS ring with COUNTED vmcnt waits (T3/T4): stage(q+2) is
// issued at the top of iteration q; the pre-barrier wait allows this
// iteration's own stage to stay in flight (vmcnt(2)/(3)) and only enforces
// stage(q+1), which has had ~2 full iterations to land -> no drain stall.
// R10 PMC showed the old __syncthreads vmcnt(0) drain was the bottleneck
// (no pipe >52% busy, TLP-doubling changed nothing: phase-locked stalls).
// Grid = 16 x 32 = 512 blocks = 2/CU (LDS 59.4 KB) = one full generation.
//
// LDS layout per buffer: 17 batches of 8 rows (1024 B); batch bb at float
// offset bb*288 + (bb&7)*4. DMA source/dest linear per instruction; the
// 16-B/batch shift spreads the K-loop's ds_read_b128 across granule columns.
// ---------------------------------------------------------------------------
#define QROWS 136
#define BATCHF 288               // floats per batch slot (1024 B data + 128 B pad)
#define BUFF (16 * BATCHF + 256) // 4864 floats = 19,456 B (batch 16 unpadded)

__global__ __launch_bounds__(512, 4) void gemm_pe_kernel(
    const float* __restrict__ x,          // (B, L, M) fp32
    const float* __restrict__ ts,         // (B, L)    fp32, sorted along L
    const unsigned short* __restrict__ wswz,
    const float* __restrict__ bias,       // (D,)
    float* __restrict__ out) {            // (B, P, D) fp32

  __shared__ float xsf[3][BUFF];          // 3 x 19,456 B = 58,368 B
  __shared__ float tsl[256];              // medians for this block's 256 patches

  const int b    = blockIdx.y;
  const int pt   = blockIdx.x;            // 0..15, patches pt*256 .. +255
  const int tid  = threadIdx.x;
  const int lane = tid & 63;
  const int wv   = tid >> 6;              // 0..7
  const int mrow = lane & 15;
  const int quad = lane >> 4;

  const float* xb0 = x + (size_t)b * Ln * Mn;   // row r -> xb0 + r*32 floats

  // ---- resident B operand: 16 fragments = 64 VGPR, loaded ONCE ------------
  // frag t: B[kk = t*32 + quad*8 + j][d0], addr = ((t*4+quad)*128 + d0)*8 + j
  const int d0 = wv * 16 + mrow;
  const unsigned short* bbase = wswz + (((quad << 7) + d0) << 3);
  bf16x8 bw[16];
  #pragma unroll
  for (int t = 0; t < 16; ++t)
    bw[t] = *reinterpret_cast<const bf16x8*>(bbase + t * 4096);

  // ---- ts medians (sorted ts -> median of 16-window = element 7) ----------
  if (tid < 256) tsl[tid] = ts[(size_t)b * Ln + (size_t)(pt * 256 + tid) * 8 + 7];

  // ---- epilogue scalars ---------------------------------------------------
  const float NEG_C = -0.14391156831212810f;            // -ln(10000)/64
  const float div0  = __expf(NEG_C * (float)(d0 >> 1));
  const float phs   = (d0 & 1) ? 1.5707963267948966f : 0.0f;
  const float bias0 = bias[d0];

  // ---- stage macro: LINEAR 1024-B/wave DMA, shifted batch bases.
  // Tail DMA source is CLAMPED in-bounds when rows >= Ln (garbage feeds only
  // discarded patch 4095) so every wave issues a compile-time-constant op
  // count: 2 per wave, +1 for wv==0  -> required for counted vmcnt waits.
#define STAGE(qq, bf)                                                          \
  do {                                                                         \
    const float* gq = xb0 + (size_t)(pt * 2048 + (qq) * 128) * 32;             \
    _Pragma("unroll")                                                          \
    for (int i = 0; i < 2; ++i) {                                              \
      const int bb = wv * 2 + i;                                               \
      gload_lds16(gq + (size_t)bb * 256 + lane * 4,                            \
                  &xsf[bf][bb * BATCHF + (bb & 7) * 4]);                       \
    }                                                                          \
    if (wv == 0) {                                                             \
      const float* gt = (pt * 2048 + (qq) * 128 + QROWS <= Ln) ? gq + 4096     \
                                                               : gq;          \
      gload_lds16(gt + lane * 4, &xsf[bf][16 * BATCHF]);                       \
    }                                                                          \
  } while (0)

  // ---- pipeline prologue: two stages in flight, wait only for the first ---
  STAGE(0, 0);
  STAGE(1, 1);
  if (wv == 0) asm volatile("s_waitcnt vmcnt(3) lgkmcnt(0)" ::: "memory");
  else         asm volatile("s_waitcnt vmcnt(2) lgkmcnt(0)" ::: "memory");
  __builtin_amdgcn_s_barrier();
  __builtin_amdgcn_sched_barrier(0);

  int rb = 0;                             // read-buffer index (q % 3)
  #pragma unroll 1
  for (int q = 0; q < 16; ++q) {
    if (q < 14) {
      int sb = rb + 2; if (sb >= 3) sb -= 3;
      STAGE(q + 2, sb);
    }
    __builtin_amdgcn_sched_barrier(0);   // pin stage-issue above the K-loop

    // ---- K-loop: 16 steps of K=32 over buf rb; zero global loads ----------
    const float* xbuf = xsf[rb];
    f32x4 acc = {0.f, 0.f, 0.f, 0.f};
    #pragma unroll
    for (int t = 0; t < 16; ++t) {
      // A-frag row r = mrow*8 + t -> batch b0 = mrow + (t>>3), row-in-batch t&7
      const int b0 = mrow + (t >> 3);
      const int fo = b0 * BATCHF + ((b0 & 7) + (t & 7) * 8 + quad * 2) * 4;
      f32x4 af0 = *reinterpret_cast<const f32x4*>(&xbuf[fo]);
      f32x4 af1 = *reinterpret_cast<const f32x4*>(&xbuf[fo + 4]);
      BU bu;
      bu.u[0] = f2bf(af0[0]); bu.u[1] = f2bf(af0[1]);
      bu.u[2] = f2bf(af0[2]); bu.u[3] = f2bf(af0[3]);
      bu.u[4] = f2bf(af1[0]); bu.u[5] = f2bf(af1[1]);
      bu.u[6] = f2bf(af1[2]); bu.u[7] = f2bf(af1[3]);
      acc = __builtin_amdgcn_mfma_f32_16x16x32_bf16(bu.v, bw[t], acc, 0, 0, 0);
    }

    // ---- counted wait BEFORE stores: allow this iteration's stage (2/3) to
    // stay in flight; enforces stage(q+1) (issued last iter, ~2 iters old).
    // vmcnt retires in order, so outstanding<=N with N = newer-op-count
    // implies the older stage completed.
    if (q < 15) {
      if (q < 14) {
        if (wv == 0) asm volatile("s_waitcnt vmcnt(3)" ::: "memory");
        else         asm volatile("s_waitcnt vmcnt(2)" ::: "memory");
      } else {
        asm volatile("s_waitcnt vmcnt(0)" ::: "memory");   // no stage issued
      }
    }

    // ---- epilogue: + bias + PE.  C/D: col=lane&15 (=d), row=quad*4+reg ----
    {
      const int plb = quad * 4;
      f32x4 med4 = *reinterpret_cast<const f32x4*>(&tsl[q * 16 + plb]);
      const int pg = pt * 256 + q * 16 + plb;
      float* obase = out + ((size_t)b * Pn + pg) * Dn + d0;
      #pragma unroll
      for (int reg = 0; reg < 4; ++reg) {
        if (pg + reg < Pn) {
          float m = med4[reg];
          obase[reg * Dn] = acc[reg] + bias0 + __sinf(m * div0 + phs);
        }
      }
    }

    if (q < 15) {
      __builtin_amdgcn_s_barrier();          // raw barrier: NO vmcnt drain
      __builtin_amdgcn_sched_barrier(0);     // fence: no ds_read hoist above
    }
    rb = (rb == 2) ? 0 : rb + 1;
  }
#undef STAGE
}

extern "C" void kernel_launch(void* const* d_in, const int* in_sizes, int n_in,
                              void* d_out, int out_size, void* d_ws, size_t ws_size,
                              hipStream_t stream) {
  const float* x      = (const float*)d_in[0];   // (32, 32768, 32)
  const float* ts     = (const float*)d_in[1];   // (32, 32768)
  const float* conv_w = (const float*)d_in[2];   // (128, 32, 16)
  const float* conv_b = (const float*)d_in[3];   // (128,)
  float* out = (float*)d_out;
  unsigned short* wswz = (unsigned short*)d_ws;  // 512*128 bf16 = 128 KiB

  prep_w_kernel<<<256, 256, 0, stream>>>(conv_w, wswz);
  gemm_pe_kernel<<<dim3(16, Bn), 512, 0, stream>>>(x, ts, wswz, conv_b, out);
}

// Round 13
// 224.145 us; speedup vs baseline: 1.0110x; 1.0099x over previous
//
#include <hip/hip_runtime.h>
#include <hip/hip_bf16.h>

// Problem constants: B,L,M,D,K,STRIDE = 32,32768,32,128,16,8
#define Bn 32
#define Ln 32768
#define Mn 32
#define Dn 128
#define Pn 4095            // (L - K)/STRIDE + 1

typedef short  bf16x8 __attribute__((ext_vector_type(8)));  // 8 bf16 = 4 VGPRs
typedef float  f32x4  __attribute__((ext_vector_type(4)));

union BU { bf16x8 v; unsigned short u[8]; };

static __device__ __forceinline__ unsigned short f2bf(float f) {
  __hip_bfloat16 h = __float2bfloat16(f);
  return *reinterpret_cast<unsigned short*>(&h);
}

// async 16-B/lane global->LDS DMA. Source must be LINEAR per lane (lane*16)
// or the DMA coalescer fragments into per-sector fetches (R3: 4x FETCH).
static __device__ __forceinline__ void gload_lds16(const float* g, float* l) {
  __builtin_amdgcn_global_load_lds(
      (const __attribute__((address_space(1))) unsigned int*)g,
      (__attribute__((address_space(3))) unsigned int*)l, 16, 0, 0);
}

// ---------------------------------------------------------------------------
// Prep: conv_w (D,M,K) fp32 -> fragment-ready swizzled bf16 in d_ws.
// kk = k*32 + m; B-frag lane d=lane&15, kk=t*32+quad*8+j
//   -> wswz[((kk>>3)*128 + d)*8 + (kk&7)]  (one 16-B load per fragment)
// ---------------------------------------------------------------------------
__global__ __launch_bounds__(256) void prep_w_kernel(const float* __restrict__ w,
                                                     unsigned short* __restrict__ wswz) {
  int idx = blockIdx.x * 256 + threadIdx.x;   // 0..65535
  int j = idx & 7;
  int d = (idx >> 3) & 127;
  int g = idx >> 10;
  int kk = g * 8 + j;
  int k = kk >> 5;
  int m = kk & 31;
  wswz[idx] = f2bf(w[(d << 9) + (m << 4) + k]);   // w[d][m][k]
}

// ---------------------------------------------------------------------------
// Main: 256 threads = 4 waves; wave wv owns 32 d-cols [wv*32, wv*32+32) as
// TWO 16-col MFMA tiles (d0, d0+16), with the full-K B operand for BOTH
// resident in 128 regs (AGPR-allocated: R11 measured VGPR_Count=60 with a
// 64-reg bw[] -> compiler places MFMA operands in AGPRs; gfx950 MFMA reads
// B from AGPR directly). Each A-fragment ds_read now feeds 2 MFMAs ->
// per-CU LDS-read instrs HALVE (R7-R11 all ~79us with LDS-pipe ~70% busy =
// 2 b128/MFMA; sync & TLP proven neutral in R10/R11).
// Block owns 128 patches = 8 quarters of 16 patches (136 rows), staged via
// global_load_lds, double-buffered, simple drain sync (R11: sync is neutral).
// Grid = 32 x 32 = 1024 blocks; ~190 regs -> 2 waves/EU -> 2 blocks/CU.
//
// LDS layout per buffer: 17 batches of 8 rows (1024 B); batch bb at float
// offset bb*288 + (bb&7)*4. DMA source/dest linear per instruction; the
// 16-B/batch shift spreads the K-loop's ds_read_b128 across granule columns.
// ---------------------------------------------------------------------------
#define QROWS 136
#define BATCHF 288               // floats per batch slot (1024 B data + 128 B pad)
#define BUFF (16 * BATCHF + 256) // 4864 floats = 19,456 B (batch 16 unpadded)

__global__ __launch_bounds__(256, 2) void gemm_pe_kernel(
    const float* __restrict__ x,          // (B, L, M) fp32
    const float* __restrict__ ts,         // (B, L)    fp32, sorted along L
    const unsigned short* __restrict__ wswz,
    const float* __restrict__ bias,       // (D,)
    float* __restrict__ out) {            // (B, P, D) fp32

  __shared__ float xsf[2][BUFF];          // 2 x 19,456 B = 38,912 B
  __shared__ float tsl[128];              // medians for this block's 128 patches

  const int b    = blockIdx.y;
  const int pt   = blockIdx.x;            // 0..31, patches pt*128 .. +127
  const int tid  = threadIdx.x;
  const int lane = tid & 63;
  const int wv   = tid >> 6;              // 0..3
  const int mrow = lane & 15;
  const int quad = lane >> 4;

  const float* xb0 = x + (size_t)b * Ln * Mn;   // row r -> xb0 + r*32 floats

  // ---- resident B operand: 2 tiles x 16 fragments = 128 regs, loaded ONCE -
  // tile0 frag t: B[kk = t*32 + quad*8 + j][d0]   at bbase + t*4096
  // tile1 frag t: same kk, d0+16                  at bbase + t*4096 + 128
  const int d0 = wv * 32 + mrow;
  const unsigned short* bbase = wswz + (((quad << 7) + (wv << 5) + mrow) << 3);
  bf16x8 bw0[16], bw1[16];
  #pragma unroll
  for (int t = 0; t < 16; ++t) {
    bw0[t] = *reinterpret_cast<const bf16x8*>(bbase + t * 4096);
    bw1[t] = *reinterpret_cast<const bf16x8*>(bbase + 128 + t * 4096);
  }

  // ---- ts medians (sorted ts -> median of 16-window = element 7) ----------
  if (tid < 128) tsl[tid] = ts[(size_t)b * Ln + (size_t)(pt * 128 + tid) * 8 + 7];

  // ---- epilogue scalars ---------------------------------------------------
  const float NEG_C = -0.14391156831212810f;            // -ln(10000)/64
  const float div0  = __expf(NEG_C * (float)(d0 >> 1));
  const float div1  = __expf(NEG_C * (float)((d0 + 16) >> 1));
  const float phs   = (d0 & 1) ? 1.5707963267948966f : 0.0f;
  const float bias0 = bias[d0];
  const float bias1 = bias[d0 + 16];

  // ---- stage macro: LINEAR 1024-B/wave DMA, shifted batch bases -----------
#define STAGE(qq, bf)                                                          \
  do {                                                                         \
    const float* gq = xb0 + (size_t)(pt * 1024 + (qq) * 128) * 32;             \
    _Pragma("unroll")                                                          \
    for (int i = 0; i < 4; ++i) {                                              \
      const int bb = i * 4 + wv;                                               \
      gload_lds16(gq + (size_t)bb * 256 + lane * 4,                            \
                  &xsf[bf][bb * BATCHF + (bb & 7) * 4]);                       \
    }                                                                          \
    if (wv == 0 && pt * 1024 + (qq) * 128 + QROWS <= Ln)                       \
      gload_lds16(gq + 4096 + lane * 4, &xsf[bf][16 * BATCHF]);                \
  } while (0)

  STAGE(0, 0);
  __syncthreads();   // drains vmcnt: Q0 + bw preloads landed

  #pragma unroll 1
  for (int q = 0; q < 8; ++q) {
    if (q < 7) STAGE(q + 1, (q + 1) & 1);
    __builtin_amdgcn_sched_barrier(0);   // pin stage-issue above the K-loop

    // ---- K-loop: 16 steps of K=32 over buf q&1; 1 A-read feeds 2 MFMAs ----
    const float* xbuf = xsf[q & 1];
    f32x4 acc0 = {0.f, 0.f, 0.f, 0.f};
    f32x4 acc1 = {0.f, 0.f, 0.f, 0.f};
    #pragma unroll
    for (int t = 0; t < 16; ++t) {
      // A-frag row r = mrow*8 + t -> batch b0 = mrow + (t>>3), row-in-batch t&7
      const int b0 = mrow + (t >> 3);
      const int fo = b0 * BATCHF + ((b0 & 7) + (t & 7) * 8 + quad * 2) * 4;
      f32x4 af0 = *reinterpret_cast<const f32x4*>(&xbuf[fo]);
      f32x4 af1 = *reinterpret_cast<const f32x4*>(&xbuf[fo + 4]);
      BU bu;
      bu.u[0] = f2bf(af0[0]); bu.u[1] = f2bf(af0[1]);
      bu.u[2] = f2bf(af0[2]); bu.u[3] = f2bf(af0[3]);
      bu.u[4] = f2bf(af1[0]); bu.u[5] = f2bf(af1[1]);
      bu.u[6] = f2bf(af1[2]); bu.u[7] = f2bf(af1[3]);
      acc0 = __builtin_amdgcn_mfma_f32_16x16x32_bf16(bu.v, bw0[t], acc0, 0, 0, 0);
      acc1 = __builtin_amdgcn_mfma_f32_16x16x32_bf16(bu.v, bw1[t], acc1, 0, 0, 0);
    }

    // ---- epilogue: + bias + PE.  C/D: col=lane&15 (=d), row=quad*4+reg ----
    {
      const int plb = quad * 4;
      f32x4 med4 = *reinterpret_cast<const f32x4*>(&tsl[q * 16 + plb]);
      const int pg = pt * 128 + q * 16 + plb;
      float* obase = out + ((size_t)b * Pn + pg) * Dn + d0;
      #pragma unroll
      for (int reg = 0; reg < 4; ++reg) {
        if (pg + reg < Pn) {
          float m = med4[reg];
          obase[reg * Dn]      = acc0[reg] + bias0 + __sinf(m * div0 + phs);
          obase[reg * Dn + 16] = acc1[reg] + bias1 + __sinf(m * div1 + phs);
        }
      }
    }

    __syncthreads();   // drains vmcnt (stage landed under K-loop) + LDS order
  }
#undef STAGE
}

extern "C" void kernel_launch(void* const* d_in, const int* in_sizes, int n_in,
                              void* d_out, int out_size, void* d_ws, size_t ws_size,
                              hipStream_t stream) {
  const float* x      = (const float*)d_in[0];   // (32, 32768, 32)
  const float* ts     = (const float*)d_in[1];   // (32, 32768)
  const float* conv_w = (const float*)d_in[2];   // (128, 32, 16)
  const float* conv_b = (const float*)d_in[3];   // (128,)
  float* out = (float*)d_out;
  unsigned short* wswz = (unsigned short*)d_ws;  // 512*128 bf16 = 128 KiB

  prep_w_kernel<<<256, 256, 0, stream>>>(conv_w, wswz);
  gemm_pe_kernel<<<dim3(32, Bn), 256, 0, stream>>>(x, ts, wswz, conv_b, out);
}